// Round 7
// baseline (768.408 us; speedup 1.0000x reference)
//
#include <hip/hip_runtime.h>
#include <cstdint>
#include <cstddef>

#define PP 2048
#define KK 10
#define HH 512
#define NPK (PP*KK)       // 20480
#define ENT_PAD 10112     // 79*128
#define REL_PAD 256
#define HALF_PAIRS 1024
#define HALF_ROWS (HALF_PAIRS*KK)  // 10240

using f32x4  = __attribute__((ext_vector_type(4))) float;
using short8 = __attribute__((ext_vector_type(8))) short;

__device__ __forceinline__ float sigf(float x) { return 1.0f / (1.0f + expf(-x)); }

__device__ __forceinline__ ushort f2bf(float x) {
    union { float f; uint32_t u; } v; v.f = x;
    uint32_t r = v.u + 0x7FFF + ((v.u >> 16) & 1);
    return (ushort)(r >> 16);
}
__device__ __forceinline__ float bf2f(ushort u) {
    union { uint32_t u; float f; } v; v.u = ((uint32_t)u) << 16;
    return v.f;
}

// perm_p[p]: p = uh*64 + g*16 + ul -> old = g*512 + uh*16 + ul   (GEMM B / whhB layout)
// perm_q[q]: q = u*4 + g           -> old = g*512 + u            (gate-table layout)
// bihh_q[q] = b_ih[old] + b_hh[old]
__global__ __launch_bounds__(256) void perm_bias2(int* __restrict__ perm_p,
                                                  int* __restrict__ perm_q,
                                                  float* __restrict__ bihh_q,
                                                  const float* __restrict__ b_ih,
                                                  const float* __restrict__ b_hh) {
    int i = blockIdx.x * 256 + threadIdx.x;
    if (i < 2048) {
        int uh = i >> 6, g = (i >> 4) & 3, ul = i & 15;
        perm_p[i] = g * 512 + uh * 16 + ul;
        int u = i >> 2, gq = i & 3;
        int oldq = gq * 512 + u;
        perm_q[i] = oldq;
        bihh_q[i] = b_ih[oldq] + b_hh[oldq];
    }
}

// ---------------- tiled transpose: dst[C][R] = src[R][C] ----------------
__global__ __launch_bounds__(256) void transpose_k(const float* __restrict__ src,
                                                   float* __restrict__ dst, int R, int C) {
    __shared__ float t[32][33];
    int bx = blockIdx.x * 32, by = blockIdx.y * 32;
    int x = threadIdx.x & 31, y = threadIdx.x >> 5;
    for (int i = y; i < 32; i += 8) {
        int r = by + i, c = bx + x;
        if (r < R && c < C) t[i][x] = src[(size_t)r * C + c];
    }
    __syncthreads();
    for (int i = y; i < 32; i += 8) {
        int c = bx + i, r = by + x;
        if (r < R && c < C) dst[(size_t)c * R + r] = t[x][i];
    }
}

// ------------- out[j] = dot(A[j,:Kd], vec) + add1[j] -------------
__global__ __launch_bounds__(256) void rowdot(const float* __restrict__ A, int lda,
                                              const float* __restrict__ vec, int Kd,
                                              const float* __restrict__ add1,
                                              float* __restrict__ out, int M) {
    int w = threadIdx.x >> 6, lane = threadIdx.x & 63;
    int row = blockIdx.x * 4 + w;
    if (row >= M) return;
    float acc = 0.f;
    for (int k = lane; k < Kd; k += 64) acc += A[(size_t)row * lda + k] * vec[k];
    for (int off = 32; off; off >>= 1) acc += __shfl_down(acc, off, 64);
    if (lane == 0) {
        float r = acc;
        if (add1) r += add1[row];
        out[row] = r;
    }
}

// ---- 2D strided fp32 -> (hi,lo) bf16 split, optional row perm, zero row padding ----
__global__ __launch_bounds__(256) void f2bf_split2d(const float* __restrict__ src,
                                                    int lda, int col0,
                                                    ushort* __restrict__ hi,
                                                    ushort* __restrict__ lo,
                                                    int nsrc_rows, int ncols, int ndst_rows,
                                                    const int* __restrict__ perm) {
    int i = blockIdx.x * 256 + threadIdx.x;
    int nc4 = ncols >> 2;
    if (i >= ndst_rows * nc4) return;
    int row = i / nc4, c4 = i % nc4;
    ushort4 h = make_ushort4(0, 0, 0, 0), l = make_ushort4(0, 0, 0, 0);
    if (row < nsrc_rows) {
        int sr = perm ? perm[row] : row;
        float4 v = *reinterpret_cast<const float4*>(src + (size_t)sr * lda + col0 + c4 * 4);
        h = make_ushort4(f2bf(v.x), f2bf(v.y), f2bf(v.z), f2bf(v.w));
        l = make_ushort4(f2bf(v.x - bf2f(h.x)), f2bf(v.y - bf2f(h.y)),
                         f2bf(v.z - bf2f(h.z)), f2bf(v.w - bf2f(h.w)));
    }
    reinterpret_cast<ushort4*>(hi)[i] = h;
    reinterpret_cast<ushort4*>(lo)[i] = l;
}

// ---- fp32 -> bf16 bulk (n4 float4 groups) ----
__global__ __launch_bounds__(256) void f2bf_k(const float* __restrict__ s,
                                              ushort* __restrict__ d, int n4) {
    int i = blockIdx.x * 256 + threadIdx.x;
    if (i < n4) {
        float4 v = reinterpret_cast<const float4*>(s)[i];
        reinterpret_cast<ushort4*>(d)[i] = make_ushort4(f2bf(v.x), f2bf(v.y), f2bf(v.z), f2bf(v.w));
    }
}

// ---- permuted-row fp32 -> bf16 (w_hh -> whhB) ----
__global__ __launch_bounds__(256) void f2bf_perm_rows(const float* __restrict__ s,
                                                      ushort* __restrict__ d,
                                                      const int* __restrict__ perm,
                                                      int nrows, int ncols4) {
    int i = blockIdx.x * 256 + threadIdx.x;
    if (i >= nrows * ncols4) return;
    int row = i / ncols4, c4 = i % ncols4;
    int sr = perm[row];
    float4 v = reinterpret_cast<const float4*>(s + (size_t)sr * ncols4 * 4)[c4];
    reinterpret_cast<ushort4*>(d + (size_t)row * ncols4 * 4)[c4] =
        make_ushort4(f2bf(v.x), f2bf(v.y), f2bf(v.z), f2bf(v.w));
}

// ---------------- bf16 MFMA GEMM: C[M,N](f32) = A@B^T (+bias). M,N%128==0, K%64==0 ----
__global__ __launch_bounds__(256) void gemm_bf16(
    const ushort* __restrict__ A, const ushort* __restrict__ B,
    float* __restrict__ C, int M, int N, int K, int ldc,
    const float* __restrict__ bias)
{
    __shared__ ushort As[128 * 64];
    __shared__ ushort Bs[128 * 64];
    int tid = threadIdx.x;
    int lane = tid & 63;
    int w = tid >> 6;
    int wr = w >> 1, wc = w & 1;
    int col0 = blockIdx.x * 128, row0 = blockIdx.y * 128;

    f32x4 acc[4][4];
#pragma unroll
    for (int m = 0; m < 4; ++m)
#pragma unroll
        for (int n = 0; n < 4; ++n) acc[m][n] = {0.f, 0.f, 0.f, 0.f};

    int rA = lane & 15;
    int kq = lane >> 4;

    for (int kt = 0; kt < K; kt += 64) {
#pragma unroll
        for (int it = 0; it < 4; ++it) {
            int c = it * 256 + tid;
            int row = c >> 3, ch = c & 7;
            int cs = ch ^ (row & 7);
            uint4 va = *reinterpret_cast<const uint4*>(A + (size_t)(row0 + row) * K + kt + ch * 8);
            *reinterpret_cast<uint4*>(&As[(size_t)row * 64 + cs * 8]) = va;
            uint4 vb = *reinterpret_cast<const uint4*>(B + (size_t)(col0 + row) * K + kt + ch * 8);
            *reinterpret_cast<uint4*>(&Bs[(size_t)row * 64 + cs * 8]) = vb;
        }
        __syncthreads();
#pragma unroll
        for (int s = 0; s < 2; ++s) {
            int csw = (s * 4 + kq) ^ (rA & 7);
            short8 af[4], bfr[4];
#pragma unroll
            for (int m = 0; m < 4; ++m) {
                int rowA = wr * 64 + m * 16 + rA;
                af[m] = *reinterpret_cast<const short8*>(&As[(size_t)rowA * 64 + csw * 8]);
            }
#pragma unroll
            for (int n = 0; n < 4; ++n) {
                int rowB = wc * 64 + n * 16 + rA;
                bfr[n] = *reinterpret_cast<const short8*>(&Bs[(size_t)rowB * 64 + csw * 8]);
            }
#pragma unroll
            for (int m = 0; m < 4; ++m)
#pragma unroll
                for (int n = 0; n < 4; ++n)
                    acc[m][n] = __builtin_amdgcn_mfma_f32_16x16x32_bf16(af[m], bfr[n], acc[m][n], 0, 0, 0);
        }
        __syncthreads();
    }
#pragma unroll
    for (int n = 0; n < 4; ++n) {
        int gcol = col0 + wc * 64 + n * 16 + rA;
        float bv = bias ? bias[gcol] : 0.f;
#pragma unroll
        for (int m = 0; m < 4; ++m) {
            int grow0 = row0 + wr * 64 + m * 16 + kq * 4;
#pragma unroll
            for (int r = 0; r < 4; ++r)
                C[(size_t)(grow0 + r) * ldc + gcol] = acc[m][n][r] + bv;
        }
    }
}

// ------------- split-bf16 GEMM (fp32-accuracy): acc = Ah.Bh^T + Ah.Bl^T + Al.Bh^T + bias
// Output: fp32 C (if non-null) and/or bf16 hi/lo pair (if Chi non-null).
__global__ __launch_bounds__(256) void gemm_bf16s(
    const ushort* __restrict__ Ah, const ushort* __restrict__ Al,
    const ushort* __restrict__ Bh, const ushort* __restrict__ Bl,
    float* __restrict__ C, ushort* __restrict__ Chi, ushort* __restrict__ Clo,
    int M, int N, int K, int ldc,
    const float* __restrict__ bias)
{
    __shared__ ushort Ash[128 * 64];
    __shared__ ushort Asl[128 * 64];
    __shared__ ushort Bsh[128 * 64];
    __shared__ ushort Bsl[128 * 64];
    int tid = threadIdx.x;
    int lane = tid & 63;
    int w = tid >> 6;
    int wr = w >> 1, wc = w & 1;
    int col0 = blockIdx.x * 128, row0 = blockIdx.y * 128;

    f32x4 acc[4][4];
#pragma unroll
    for (int m = 0; m < 4; ++m)
#pragma unroll
        for (int n = 0; n < 4; ++n) acc[m][n] = {0.f, 0.f, 0.f, 0.f};

    int rA = lane & 15;
    int kq = lane >> 4;

    for (int kt = 0; kt < K; kt += 64) {
#pragma unroll
        for (int it = 0; it < 4; ++it) {
            int c = it * 256 + tid;
            int row = c >> 3, ch = c & 7;
            int cs = ch ^ (row & 7);
            size_t ga = (size_t)(row0 + row) * K + kt + ch * 8;
            size_t gb = (size_t)(col0 + row) * K + kt + ch * 8;
            size_t la = (size_t)row * 64 + cs * 8;
            *reinterpret_cast<uint4*>(&Ash[la]) = *reinterpret_cast<const uint4*>(Ah + ga);
            *reinterpret_cast<uint4*>(&Asl[la]) = *reinterpret_cast<const uint4*>(Al + ga);
            *reinterpret_cast<uint4*>(&Bsh[la]) = *reinterpret_cast<const uint4*>(Bh + gb);
            *reinterpret_cast<uint4*>(&Bsl[la]) = *reinterpret_cast<const uint4*>(Bl + gb);
        }
        __syncthreads();
#pragma unroll
        for (int s = 0; s < 2; ++s) {
            int csw = (s * 4 + kq) ^ (rA & 7);
            short8 xh[4], yh[4], t4[4];
#pragma unroll
            for (int m = 0; m < 4; ++m) {
                int rowA = wr * 64 + m * 16 + rA;
                xh[m] = *reinterpret_cast<const short8*>(&Ash[(size_t)rowA * 64 + csw * 8]);
            }
#pragma unroll
            for (int n = 0; n < 4; ++n) {
                int rowB = wc * 64 + n * 16 + rA;
                yh[n] = *reinterpret_cast<const short8*>(&Bsh[(size_t)rowB * 64 + csw * 8]);
            }
#pragma unroll
            for (int m = 0; m < 4; ++m)
#pragma unroll
                for (int n = 0; n < 4; ++n)
                    acc[m][n] = __builtin_amdgcn_mfma_f32_16x16x32_bf16(xh[m], yh[n], acc[m][n], 0, 0, 0);
#pragma unroll
            for (int n = 0; n < 4; ++n) {
                int rowB = wc * 64 + n * 16 + rA;
                t4[n] = *reinterpret_cast<const short8*>(&Bsl[(size_t)rowB * 64 + csw * 8]);
            }
#pragma unroll
            for (int m = 0; m < 4; ++m)
#pragma unroll
                for (int n = 0; n < 4; ++n)
                    acc[m][n] = __builtin_amdgcn_mfma_f32_16x16x32_bf16(xh[m], t4[n], acc[m][n], 0, 0, 0);
#pragma unroll
            for (int m = 0; m < 4; ++m) {
                int rowA = wr * 64 + m * 16 + rA;
                t4[m] = *reinterpret_cast<const short8*>(&Asl[(size_t)rowA * 64 + csw * 8]);
            }
#pragma unroll
            for (int m = 0; m < 4; ++m)
#pragma unroll
                for (int n = 0; n < 4; ++n)
                    acc[m][n] = __builtin_amdgcn_mfma_f32_16x16x32_bf16(t4[m], yh[n], acc[m][n], 0, 0, 0);
        }
        __syncthreads();
    }
#pragma unroll
    for (int n = 0; n < 4; ++n) {
        int gcol = col0 + wc * 64 + n * 16 + rA;
        float bv = bias ? bias[gcol] : 0.f;
#pragma unroll
        for (int m = 0; m < 4; ++m) {
            int grow0 = row0 + wr * 64 + m * 16 + kq * 4;
#pragma unroll
            for (int r = 0; r < 4; ++r) {
                float v = acc[m][n][r] + bv;
                size_t idx = (size_t)(grow0 + r) * ldc + gcol;
                if (C) C[idx] = v;
                if (Chi) {
                    ushort h = f2bf(v);
                    Chi[idx] = h;
                    Clo[idx] = f2bf(v - bf2f(h));
                }
            }
        }
    }
}

// ---------------- FUSED: G = h_in@whhB^T, LSTM pointwise epilogue. Full-size. -------
// M=NPK(20480), N=2048 (B rows = perm_p gate layout), K=512. Flat grid 2560 with
// XCD-aware swizzle: swz=(L&7)*320+(L>>3) -> each XCD owns 20 consecutive row-groups
// so the 16 col-blocks sharing A-rows hit the same L2 (A slice 2.6 MB < 4 MB L2).
// Gate tables are UNIT-MAJOR (q = u*4+g): epilogue reads ONE float4 per table.
// h ping-pong: A (h at t-1) and hbuf (h at t) MUST differ (cross-block race).
__global__ __launch_bounds__(256) void gemm_lstm(
    const ushort* __restrict__ A, const ushort* __restrict__ B,
    const float* __restrict__ relg, const float* __restrict__ entg,
    const int* __restrict__ rel_idx, const int* __restrict__ ent_idx,
    const int* __restrict__ lens_,
    ushort* __restrict__ hbuf, float* __restrict__ cbuf, ushort* __restrict__ pemb,
    int t)
{
    __shared__ ushort As[128 * 64];
    __shared__ ushort Bs[128 * 64];
    const int K = 512;
    int L = blockIdx.x;
    int swz = (L & 7) * 320 + (L >> 3);
    int bx = swz & 15, by = swz >> 4;
    int tid = threadIdx.x;
    int lane = tid & 63;
    int w = tid >> 6;
    int wr = w >> 1, wc = w & 1;
    int col0 = bx * 128, row0 = by * 128;

    f32x4 acc[4][4];
#pragma unroll
    for (int m = 0; m < 4; ++m)
#pragma unroll
        for (int n = 0; n < 4; ++n) acc[m][n] = {0.f, 0.f, 0.f, 0.f};

    int rA = lane & 15;
    int kq = lane >> 4;

    for (int kt = 0; kt < K; kt += 64) {
#pragma unroll
        for (int it = 0; it < 4; ++it) {
            int c = it * 256 + tid;
            int row = c >> 3, ch = c & 7;
            int cs = ch ^ (row & 7);
            uint4 va = *reinterpret_cast<const uint4*>(A + (size_t)(row0 + row) * K + kt + ch * 8);
            *reinterpret_cast<uint4*>(&As[(size_t)row * 64 + cs * 8]) = va;
            uint4 vb = *reinterpret_cast<const uint4*>(B + (size_t)(col0 + row) * K + kt + ch * 8);
            *reinterpret_cast<uint4*>(&Bs[(size_t)row * 64 + cs * 8]) = vb;
        }
        __syncthreads();
#pragma unroll
        for (int s = 0; s < 2; ++s) {
            int csw = (s * 4 + kq) ^ (rA & 7);
            short8 af[4], bfr[4];
#pragma unroll
            for (int m = 0; m < 4; ++m) {
                int rowA = wr * 64 + m * 16 + rA;
                af[m] = *reinterpret_cast<const short8*>(&As[(size_t)rowA * 64 + csw * 8]);
            }
#pragma unroll
            for (int n = 0; n < 4; ++n) {
                int rowB = wc * 64 + n * 16 + rA;
                bfr[n] = *reinterpret_cast<const short8*>(&Bs[(size_t)rowB * 64 + csw * 8]);
            }
#pragma unroll
            for (int m = 0; m < 4; ++m)
#pragma unroll
                for (int n = 0; n < 4; ++n)
                    acc[m][n] = __builtin_amdgcn_mfma_f32_16x16x32_bf16(af[m], bfr[n], acc[m][n], 0, 0, 0);
        }
        __syncthreads();
    }

    // fused LSTM epilogue: lane owns unit u = uh*16+rA; acc[m][0..3] = i,f,g,o gates
    int uh = bx * 2 + wc;
    int u  = uh * 16 + rA;
    const float4* rel4 = reinterpret_cast<const float4*>(relg);
    const float4* ent4 = reinterpret_cast<const float4*>(entg);
#pragma unroll
    for (int m = 0; m < 4; ++m) {
#pragma unroll
        for (int r = 0; r < 4; ++r) {
            int n = row0 + wr * 64 + m * 16 + kq * 4 + r;   // global path row
            int ri = rel_idx[n * 3 + t];
            int ei = ent_idx[n * 3 + t];
            float4 rv = rel4[(size_t)ri * 512 + u];
            float4 ev = ent4[(size_t)ei * 512 + u];
            float gi = acc[m][0][r] + rv.x + ev.x;
            float gf = acc[m][1][r] + rv.y + ev.y;
            float gg = acc[m][2][r] + rv.z + ev.z;
            float go = acc[m][3][r] + rv.w + ev.w;
            float cold = cbuf[(size_t)n * 512 + u];
            float cn = sigf(gf) * cold + sigf(gi) * tanhf(gg);
            float hn = sigf(go) * tanhf(cn);
            cbuf[(size_t)n * 512 + u] = cn;
            ushort hu = f2bf(hn);
            hbuf[(size_t)n * 512 + u] = hu;
            int len = lens_[n];
            int last = len - 1;
            if (last < 0) last = 0;
            if (last > 2) last = 2;
            if (last == t) pemb[(size_t)n * 512 + u] = (len > 0) ? hu : (ushort)0;
        }
    }
}

// ---------------- LSTM t=0 (no recurrent term), unit-major gate tables --------------
// Thread handles 4 consecutive units of one row: reads 4 float4 (64B contiguous)/table.
__global__ __launch_bounds__(256) void lstm_t0(
    const float* __restrict__ relg, const float* __restrict__ entg,
    const int* __restrict__ rel_idx, const int* __restrict__ ent_idx,
    const int* __restrict__ lens_,
    ushort* __restrict__ hbuf, float* __restrict__ cbuf, ushort* __restrict__ pemb,
    int nrows)
{
    int gid = blockIdx.x * 256 + threadIdx.x;
    if (gid >= nrows * 128) return;
    int nl = gid >> 7, q = gid & 127;   // units q*4 .. q*4+3
    int ri = rel_idx[nl * 3];
    int ei = ent_idx[nl * 3];
    const float4* rg = reinterpret_cast<const float4*>(relg) + (size_t)ri * 512;
    const float4* eg = reinterpret_cast<const float4*>(entg) + (size_t)ei * 512;
    float4 cn, hn;
#pragma unroll
    for (int j = 0; j < 4; ++j) {
        float4 a = rg[q * 4 + j];
        float4 b = eg[q * 4 + j];
        float gi = a.x + b.x, gg = a.z + b.z, go = a.w + b.w;   // f unused (c0=0)
        float c = sigf(gi) * tanhf(gg);
        float h = sigf(go) * tanhf(c);
        (&cn.x)[j] = c;
        (&hn.x)[j] = h;
    }
    reinterpret_cast<float4*>(cbuf + (size_t)nl * 512)[q] = cn;
    ushort4 hu = make_ushort4(f2bf(hn.x), f2bf(hn.y), f2bf(hn.z), f2bf(hn.w));
    reinterpret_cast<ushort4*>(hbuf + (size_t)nl * 512)[q] = hu;
    int len = lens_[nl];
    int last = len - 1;
    if (last < 0) last = 0;
    if (last > 2) last = 2;
    if (last == 0) {
        ushort4 pv = (len > 0) ? hu : make_ushort4(0, 0, 0, 0);
        reinterpret_cast<ushort4*>(pemb + (size_t)nl * 512)[q] = pv;
    }
}

// ---------------- per-pair attention -> mean-over-q context (bf16 hi/lo out) --------
__global__ __launch_bounds__(256) void attn_kernel(const float* __restrict__ qkv,
                                                   ushort* __restrict__ mch,
                                                   ushort* __restrict__ mcl, int pair0)
{
    __shared__ float qk[10][1024];
    __shared__ float sc[4][10][10];
    __shared__ float wb[4][10];
    int tid = threadIdx.x;
    const float* base = qkv + (size_t)blockIdx.x * 10 * 1536;
    for (int i = tid; i < 2560; i += 256) {
        int row = i >> 8, c4 = i & 255;
        reinterpret_cast<float4*>(&qk[row][0])[c4] =
            reinterpret_cast<const float4*>(base + (size_t)row * 1536)[c4];
    }
    __syncthreads();
    const float scale = 0.08838834764831845f; // 1/sqrt(128)
    for (int idx = tid; idx < 400; idx += 256) {
        int h = idx / 100, rem = idx % 100, qi = rem / 10, ki = rem % 10;
        const float* qp = &qk[qi][h * 128];
        const float* kp = &qk[ki][512 + h * 128];
        float a = 0.f;
        for (int d = 0; d < 128; ++d) a += qp[d] * kp[d];
        sc[h][qi][ki] = a * scale;
    }
    __syncthreads();
    if (tid < 40) {
        int h = tid / 10, qi = tid % 10;
        float m = -1e30f;
        for (int ki = 0; ki < 10; ++ki) m = fmaxf(m, sc[h][qi][ki]);
        float ex[10]; float s = 0.f;
        for (int ki = 0; ki < 10; ++ki) { ex[ki] = expf(sc[h][qi][ki] - m); s += ex[ki]; }
        float inv = 1.f / s;
        for (int ki = 0; ki < 10; ++ki) sc[h][qi][ki] = ex[ki] * inv;
    }
    __syncthreads();
    if (tid < 40) {
        int h = tid / 10, ki = tid % 10;
        float s = 0.f;
        for (int qi = 0; qi < 10; ++qi) s += sc[h][qi][ki];
        wb[h][ki] = s * 0.1f;
    }
    __syncthreads();
    for (int e = tid; e < 512; e += 256) {
        int h = e >> 7, d = e & 127;
        float a = 0.f;
        for (int ki = 0; ki < 10; ++ki)
            a += wb[h][ki] * base[(size_t)ki * 1536 + 1024 + h * 128 + d];
        size_t idx = (size_t)(pair0 + blockIdx.x) * 512 + e;
        ushort hh = f2bf(a);
        mch[idx] = hh;
        mcl[idx] = f2bf(a - bf2f(hh));
    }
}

extern "C" void kernel_launch(void* const* d_in, const int* in_sizes, int n_in,
                              void* d_out, int out_size, void* d_ws, size_t ws_size,
                              hipStream_t stream)
{
    const int* rel_idx     = (const int*)d_in[0];
    const int* ent_idx     = (const int*)d_in[1];
    const int* path_lens   = (const int*)d_in[2];
    const float* rel_table = (const float*)d_in[3];
    const float* ent_table = (const float*)d_in[4];
    const float* kg_proj_w = (const float*)d_in[5];
    const float* kg_proj_b = (const float*)d_in[6];
    const float* w_ih      = (const float*)d_in[7];
    const float* w_hh      = (const float*)d_in[8];
    const float* b_ih      = (const float*)d_in[9];
    const float* b_hh      = (const float*)d_in[10];
    const float* attn_in_w = (const float*)d_in[11];
    const float* attn_in_b = (const float*)d_in[12];
    const float* attn_out_w = (const float*)d_in[13];
    const float* attn_out_b = (const float*)d_in[14];
    const float* path_proj_w = (const float*)d_in[15];
    const float* path_proj_b = (const float*)d_in[16];
    float* out = (float*)d_out;
    (void)in_sizes; (void)n_in; (void)out_size; (void)ws_size;

    float* ws = (float*)d_ws;
    size_t off = 0;
    auto alloc = [&](size_t n) { float* p = ws + off; off += (n + 63) & ~(size_t)63; return p; };
    // ---- persistent (float units) ----
    int*    perm_p = (int*)alloc(2048);
    int*    perm_q = (int*)alloc(2048);
    float*  bihh   = alloc(2048);
    float*  bcomb  = alloc(512);
    float*  relg   = alloc((size_t)REL_PAD * 2048);       // 2 MB (unit-major cols)
    float*  entg   = alloc((size_t)ENT_PAD * 2048);       // 82.8 MB (unit-major cols)
    ushort* whhB   = (ushort*)alloc((size_t)2048 * 256);  // 2048x512 bf16, perm_p rows
    ushort* aiwB   = (ushort*)alloc((size_t)1536 * 256);
    ushort* pch    = (ushort*)alloc((size_t)NPK * 256);   // pemb bf16, 21 MB
    ushort* Wch    = (ushort*)alloc((size_t)512 * 256);
    ushort* Wcl    = (ushort*)alloc((size_t)512 * 256);
    ushort* mch    = (ushort*)alloc((size_t)PP * 256);    // mctx hi
    ushort* mcl    = (ushort*)alloc((size_t)PP * 256);    // mctx lo
    // ---- phase-shared region (84 MB) ----
    float* R = alloc((size_t)21000000);

    // phase P (prologue temps) — dead before LSTM starts
    size_t ro = 0;
    auto ral = [&](size_t n) { float* p = R + ro; ro += n; return p; };
    ushort* kgWh  = (ushort*)ral(65536);   ushort* kgWl  = (ushort*)ral(65536);
    ushort* relBh = (ushort*)ral(32768);   ushort* relBl = (ushort*)ral(32768);
    ushort* entBh = (ushort*)ral(1294336); ushort* entBl = (ushort*)ral(1294336);
    ushort* wrelh = (ushort*)ral(524288);  ushort* wrell = (ushort*)ral(524288);
    ushort* wenth = (ushort*)ral(524288);  ushort* wentl = (ushort*)ral(524288);
    ushort* rel_ph = (ushort*)ral(65536);   ushort* rel_pl = (ushort*)ral(65536);
    ushort* ent_ph = (ushort*)ral(2588672); ushort* ent_pl = (ushort*)ral(2588672);
    float*  aoT    = ral(262144);
    ushort* pph  = (ushort*)ral(131072); ushort* ppl  = (ushort*)ral(131072);
    ushort* aoTh = (ushort*)ral(131072); ushort* aoTl = (ushort*)ral(131072);
    // phase L (LSTM): fp32 c + h ping-pong — overlays phase P
    float*  cb = R;                               // 20480*512 fp32
    ushort* hA = (ushort*)(R + 10485760);
    ushort* hB = (ushort*)(R + 15728640);
    // phase A (attn): qkv half = 10240*1536 fp32 — overlays phase L
    float*  qkv = R;

    auto split = [&](const float* src, int lda, int col0, ushort* hi, ushort* lo,
                     int nsrc, int ncols, int ndst, const int* pm) {
        int total = ndst * (ncols / 4);
        f2bf_split2d<<<(total + 255) / 256, 256, 0, stream>>>(src, lda, col0, hi, lo, nsrc, ncols, ndst, pm);
    };
    auto gemms = [&](const ushort* Ah, const ushort* Al, const ushort* Bh, const ushort* Bl,
                     float* Cp, ushort* Chi, ushort* Clo,
                     int M, int N, int Kd, int ldc, const float* bias) {
        gemm_bf16s<<<dim3((unsigned)(N / 128), (unsigned)(M / 128)), 256, 0, stream>>>(
            Ah, Al, Bh, Bl, Cp, Chi, Clo, M, N, Kd, ldc, bias);
    };

    // ======== prologue ========
    perm_bias2<<<8, 256, 0, stream>>>(perm_p, perm_q, bihh, b_ih, b_hh);
    transpose_k<<<dim3(16, 16), 256, 0, stream>>>(attn_out_w, aoT, 512, 512);
    split(kg_proj_w, 256, 0, kgWh, kgWl, 512, 256, 512, nullptr);
    split(rel_table, 256, 0, relBh, relBl, 200, 256, REL_PAD, nullptr);
    split(ent_table, 256, 0, entBh, entBl, 10000, 256, ENT_PAD, nullptr);
    split(w_ih, 1024, 0,   wrelh, wrell, 2048, 512, 2048, perm_q);   // table-build B: q layout
    split(w_ih, 1024, 512, wenth, wentl, 2048, 512, 2048, perm_q);
    split(path_proj_w, 512, 0, pph, ppl, 512, 512, 512, nullptr);
    split(aoT, 512, 0, aoTh, aoTl, 512, 512, 512, nullptr);
    f2bf_perm_rows<<<1024, 256, 0, stream>>>(w_hh, whhB, perm_p, 2048, 128); // GEMM B: p layout
    f2bf_k<<<768, 256, 0, stream>>>(attn_in_w, aiwB, 1536 * 128);
    rowdot<<<128, 256, 0, stream>>>(path_proj_w, 512, attn_out_b, 512, path_proj_b, bcomb, 512);

    // projected tables (hi/lo direct): rel_p = relT@kgW^T + b ; ent_p likewise
    gemms(relBh, relBl, kgWh, kgWl, nullptr, rel_ph, rel_pl, REL_PAD, 512, 256, 512, kg_proj_b);
    gemms(entBh, entBl, kgWh, kgWl, nullptr, ent_ph, ent_pl, ENT_PAD, 512, 256, 512, kg_proj_b);
    // gate tables (unit-major cols): relg = rel_p@Wq^T + bihh ; entg = ent_p@Wq^T
    gemms(rel_ph, rel_pl, wrelh, wrell, relg, nullptr, nullptr, REL_PAD, 2048, 512, 2048, bihh);
    gemms(ent_ph, ent_pl, wenth, wentl, entg, nullptr, nullptr, ENT_PAD, 2048, 512, 2048, nullptr);
    // Wcomb = path_proj_w @ attn_out_w (hi/lo direct)
    gemms(pph, ppl, aoTh, aoTl, nullptr, Wch, Wcl, 512, 512, 512, 512, nullptr);

    // ======== LSTM, full-size ========
    lstm_t0<<<(NPK * 128) / 256, 256, 0, stream>>>(
        relg, entg, rel_idx, ent_idx, path_lens, hA, cb, pch, NPK);
    gemm_lstm<<<2560, 256, 0, stream>>>(
        hA, whhB, relg, entg, rel_idx, ent_idx, path_lens, hB, cb, pch, 1);
    gemm_lstm<<<2560, 256, 0, stream>>>(
        hB, whhB, relg, entg, rel_idx, ent_idx, path_lens, hA, cb, pch, 2);

    // ======== qkv + attention, 2 halves ========
    for (int h = 0; h < 2; ++h) {
        gemm_bf16<<<dim3(12, 80), 256, 0, stream>>>(
            pch + (size_t)h * HALF_ROWS * 512, aiwB, qkv, HALF_ROWS, 1536, 512, 1536, attn_in_b);
        attn_kernel<<<HALF_PAIRS, 256, 0, stream>>>(qkv, mch, mcl, h * HALF_PAIRS);
    }

    // ======== out = mctx @ Wcomb^T + bcomb (split-bf16) ========
    gemms(mch, mcl, Wch, Wcl, out, nullptr, nullptr, 2048, 512, 512, 512, bcomb);
}

// Round 8
// 678.289 us; speedup vs baseline: 1.1329x; 1.1329x over previous
//
#include <hip/hip_runtime.h>
#include <cstdint>
#include <cstddef>

#define PP 2048
#define KK 10
#define HH 512
#define NPK (PP*KK)       // 20480
#define ENT_PAD 10112     // 79*128
#define REL_PAD 256
#define HALF_PAIRS 1024
#define HALF_ROWS (HALF_PAIRS*KK)  // 10240

using f32x4  = __attribute__((ext_vector_type(4))) float;
using short8 = __attribute__((ext_vector_type(8))) short;

// ---- fast transcendentals: v_exp_f32 / v_rcp_f32 based ----
__device__ __forceinline__ float fexp2(float x) {
#if __has_builtin(__builtin_amdgcn_exp2f)
    return __builtin_amdgcn_exp2f(x);
#else
    return __exp2f(x);
#endif
}
__device__ __forceinline__ float frcp(float x) {
#if __has_builtin(__builtin_amdgcn_rcpf)
    return __builtin_amdgcn_rcpf(x);
#else
    return 1.0f / x;
#endif
}
#define LOG2E  1.4426950408889634f
#define LOG2E2 2.8853900817779268f
__device__ __forceinline__ float sigf(float x) {
    return frcp(1.0f + fexp2(-LOG2E * x));
}
__device__ __forceinline__ float tanhf_f(float x) {
    float xc = fminf(fmaxf(x, -9.0f), 9.0f);
    float e = fexp2(LOG2E2 * xc);
    return (e - 1.0f) * frcp(e + 1.0f);
}

__device__ __forceinline__ ushort f2bf(float x) {
    union { float f; uint32_t u; } v; v.f = x;
    uint32_t r = v.u + 0x7FFF + ((v.u >> 16) & 1);
    return (ushort)(r >> 16);
}
__device__ __forceinline__ float bf2f(ushort u) {
    union { uint32_t u; float f; } v; v.u = ((uint32_t)u) << 16;
    return v.f;
}

// perm_p[p]: p = uh*64 + g*16 + ul -> old = g*512 + uh*16 + ul   (GEMM B / whhB layout)
// perm_q[q]: q = u*4 + g           -> old = g*512 + u            (gate-table layout)
// bihh_q[q] = b_ih[old] + b_hh[old]
__global__ __launch_bounds__(256) void perm_bias2(int* __restrict__ perm_p,
                                                  int* __restrict__ perm_q,
                                                  float* __restrict__ bihh_q,
                                                  const float* __restrict__ b_ih,
                                                  const float* __restrict__ b_hh) {
    int i = blockIdx.x * 256 + threadIdx.x;
    if (i < 2048) {
        int uh = i >> 6, g = (i >> 4) & 3, ul = i & 15;
        perm_p[i] = g * 512 + uh * 16 + ul;
        int u = i >> 2, gq = i & 3;
        int oldq = gq * 512 + u;
        perm_q[i] = oldq;
        bihh_q[i] = b_ih[oldq] + b_hh[oldq];
    }
}

// ---------------- tiled transpose: dst[C][R] = src[R][C] ----------------
__global__ __launch_bounds__(256) void transpose_k(const float* __restrict__ src,
                                                   float* __restrict__ dst, int R, int C) {
    __shared__ float t[32][33];
    int bx = blockIdx.x * 32, by = blockIdx.y * 32;
    int x = threadIdx.x & 31, y = threadIdx.x >> 5;
    for (int i = y; i < 32; i += 8) {
        int r = by + i, c = bx + x;
        if (r < R && c < C) t[i][x] = src[(size_t)r * C + c];
    }
    __syncthreads();
    for (int i = y; i < 32; i += 8) {
        int c = bx + i, r = by + x;
        if (r < R && c < C) dst[(size_t)c * R + r] = t[x][i];
    }
}

// ------------- out[j] = dot(A[j,:Kd], vec) + add1[j] -------------
__global__ __launch_bounds__(256) void rowdot(const float* __restrict__ A, int lda,
                                              const float* __restrict__ vec, int Kd,
                                              const float* __restrict__ add1,
                                              float* __restrict__ out, int M) {
    int w = threadIdx.x >> 6, lane = threadIdx.x & 63;
    int row = blockIdx.x * 4 + w;
    if (row >= M) return;
    float acc = 0.f;
    for (int k = lane; k < Kd; k += 64) acc += A[(size_t)row * lda + k] * vec[k];
    for (int off = 32; off; off >>= 1) acc += __shfl_down(acc, off, 64);
    if (lane == 0) {
        float r = acc;
        if (add1) r += add1[row];
        out[row] = r;
    }
}

// ---- 2D strided fp32 -> (hi,lo) bf16 split, optional row perm, zero row padding ----
__global__ __launch_bounds__(256) void f2bf_split2d(const float* __restrict__ src,
                                                    int lda, int col0,
                                                    ushort* __restrict__ hi,
                                                    ushort* __restrict__ lo,
                                                    int nsrc_rows, int ncols, int ndst_rows,
                                                    const int* __restrict__ perm) {
    int i = blockIdx.x * 256 + threadIdx.x;
    int nc4 = ncols >> 2;
    if (i >= ndst_rows * nc4) return;
    int row = i / nc4, c4 = i % nc4;
    ushort4 h = make_ushort4(0, 0, 0, 0), l = make_ushort4(0, 0, 0, 0);
    if (row < nsrc_rows) {
        int sr = perm ? perm[row] : row;
        float4 v = *reinterpret_cast<const float4*>(src + (size_t)sr * lda + col0 + c4 * 4);
        h = make_ushort4(f2bf(v.x), f2bf(v.y), f2bf(v.z), f2bf(v.w));
        l = make_ushort4(f2bf(v.x - bf2f(h.x)), f2bf(v.y - bf2f(h.y)),
                         f2bf(v.z - bf2f(h.z)), f2bf(v.w - bf2f(h.w)));
    }
    reinterpret_cast<ushort4*>(hi)[i] = h;
    reinterpret_cast<ushort4*>(lo)[i] = l;
}

// ---- fp32 -> bf16 bulk (n4 float4 groups) ----
__global__ __launch_bounds__(256) void f2bf_k(const float* __restrict__ s,
                                              ushort* __restrict__ d, int n4) {
    int i = blockIdx.x * 256 + threadIdx.x;
    if (i < n4) {
        float4 v = reinterpret_cast<const float4*>(s)[i];
        reinterpret_cast<ushort4*>(d)[i] = make_ushort4(f2bf(v.x), f2bf(v.y), f2bf(v.z), f2bf(v.w));
    }
}

// ---- permuted-row fp32 -> bf16 (w_hh -> whhB) ----
__global__ __launch_bounds__(256) void f2bf_perm_rows(const float* __restrict__ s,
                                                      ushort* __restrict__ d,
                                                      const int* __restrict__ perm,
                                                      int nrows, int ncols4) {
    int i = blockIdx.x * 256 + threadIdx.x;
    if (i >= nrows * ncols4) return;
    int row = i / ncols4, c4 = i % ncols4;
    int sr = perm[row];
    float4 v = reinterpret_cast<const float4*>(s + (size_t)sr * ncols4 * 4)[c4];
    reinterpret_cast<ushort4*>(d + (size_t)row * ncols4 * 4)[c4] =
        make_ushort4(f2bf(v.x), f2bf(v.y), f2bf(v.z), f2bf(v.w));
}

// ---------------- bf16 MFMA GEMM: C[M,N](f32) = A@B^T (+bias). M,N%128==0, K%64==0 ----
__global__ __launch_bounds__(256) void gemm_bf16(
    const ushort* __restrict__ A, const ushort* __restrict__ B,
    float* __restrict__ C, int M, int N, int K, int ldc,
    const float* __restrict__ bias)
{
    __shared__ ushort As[128 * 64];
    __shared__ ushort Bs[128 * 64];
    int tid = threadIdx.x;
    int lane = tid & 63;
    int w = tid >> 6;
    int wr = w >> 1, wc = w & 1;
    int col0 = blockIdx.x * 128, row0 = blockIdx.y * 128;

    f32x4 acc[4][4];
#pragma unroll
    for (int m = 0; m < 4; ++m)
#pragma unroll
        for (int n = 0; n < 4; ++n) acc[m][n] = {0.f, 0.f, 0.f, 0.f};

    int rA = lane & 15;
    int kq = lane >> 4;

    for (int kt = 0; kt < K; kt += 64) {
#pragma unroll
        for (int it = 0; it < 4; ++it) {
            int c = it * 256 + tid;
            int row = c >> 3, ch = c & 7;
            int cs = ch ^ (row & 7);
            uint4 va = *reinterpret_cast<const uint4*>(A + (size_t)(row0 + row) * K + kt + ch * 8);
            *reinterpret_cast<uint4*>(&As[(size_t)row * 64 + cs * 8]) = va;
            uint4 vb = *reinterpret_cast<const uint4*>(B + (size_t)(col0 + row) * K + kt + ch * 8);
            *reinterpret_cast<uint4*>(&Bs[(size_t)row * 64 + cs * 8]) = vb;
        }
        __syncthreads();
#pragma unroll
        for (int s = 0; s < 2; ++s) {
            int csw = (s * 4 + kq) ^ (rA & 7);
            short8 af[4], bfr[4];
#pragma unroll
            for (int m = 0; m < 4; ++m) {
                int rowA = wr * 64 + m * 16 + rA;
                af[m] = *reinterpret_cast<const short8*>(&As[(size_t)rowA * 64 + csw * 8]);
            }
#pragma unroll
            for (int n = 0; n < 4; ++n) {
                int rowB = wc * 64 + n * 16 + rA;
                bfr[n] = *reinterpret_cast<const short8*>(&Bs[(size_t)rowB * 64 + csw * 8]);
            }
#pragma unroll
            for (int m = 0; m < 4; ++m)
#pragma unroll
                for (int n = 0; n < 4; ++n)
                    acc[m][n] = __builtin_amdgcn_mfma_f32_16x16x32_bf16(af[m], bfr[n], acc[m][n], 0, 0, 0);
        }
        __syncthreads();
    }
#pragma unroll
    for (int n = 0; n < 4; ++n) {
        int gcol = col0 + wc * 64 + n * 16 + rA;
        float bv = bias ? bias[gcol] : 0.f;
#pragma unroll
        for (int m = 0; m < 4; ++m) {
            int grow0 = row0 + wr * 64 + m * 16 + kq * 4;
#pragma unroll
            for (int r = 0; r < 4; ++r)
                C[(size_t)(grow0 + r) * ldc + gcol] = acc[m][n][r] + bv;
        }
    }
}

// ------------- split-bf16 GEMM (fp32-accuracy): acc = Ah.Bh^T + Ah.Bl^T + Al.Bh^T + bias
// Output: fp32 C (if non-null) and/or bf16 hi/lo pair (if Chi non-null).
__global__ __launch_bounds__(256) void gemm_bf16s(
    const ushort* __restrict__ Ah, const ushort* __restrict__ Al,
    const ushort* __restrict__ Bh, const ushort* __restrict__ Bl,
    float* __restrict__ C, ushort* __restrict__ Chi, ushort* __restrict__ Clo,
    int M, int N, int K, int ldc,
    const float* __restrict__ bias)
{
    __shared__ ushort Ash[128 * 64];
    __shared__ ushort Asl[128 * 64];
    __shared__ ushort Bsh[128 * 64];
    __shared__ ushort Bsl[128 * 64];
    int tid = threadIdx.x;
    int lane = tid & 63;
    int w = tid >> 6;
    int wr = w >> 1, wc = w & 1;
    int col0 = blockIdx.x * 128, row0 = blockIdx.y * 128;

    f32x4 acc[4][4];
#pragma unroll
    for (int m = 0; m < 4; ++m)
#pragma unroll
        for (int n = 0; n < 4; ++n) acc[m][n] = {0.f, 0.f, 0.f, 0.f};

    int rA = lane & 15;
    int kq = lane >> 4;

    for (int kt = 0; kt < K; kt += 64) {
#pragma unroll
        for (int it = 0; it < 4; ++it) {
            int c = it * 256 + tid;
            int row = c >> 3, ch = c & 7;
            int cs = ch ^ (row & 7);
            size_t ga = (size_t)(row0 + row) * K + kt + ch * 8;
            size_t gb = (size_t)(col0 + row) * K + kt + ch * 8;
            size_t la = (size_t)row * 64 + cs * 8;
            *reinterpret_cast<uint4*>(&Ash[la]) = *reinterpret_cast<const uint4*>(Ah + ga);
            *reinterpret_cast<uint4*>(&Asl[la]) = *reinterpret_cast<const uint4*>(Al + ga);
            *reinterpret_cast<uint4*>(&Bsh[la]) = *reinterpret_cast<const uint4*>(Bh + gb);
            *reinterpret_cast<uint4*>(&Bsl[la]) = *reinterpret_cast<const uint4*>(Bl + gb);
        }
        __syncthreads();
#pragma unroll
        for (int s = 0; s < 2; ++s) {
            int csw = (s * 4 + kq) ^ (rA & 7);
            short8 xh[4], yh[4], t4[4];
#pragma unroll
            for (int m = 0; m < 4; ++m) {
                int rowA = wr * 64 + m * 16 + rA;
                xh[m] = *reinterpret_cast<const short8*>(&Ash[(size_t)rowA * 64 + csw * 8]);
            }
#pragma unroll
            for (int n = 0; n < 4; ++n) {
                int rowB = wc * 64 + n * 16 + rA;
                yh[n] = *reinterpret_cast<const short8*>(&Bsh[(size_t)rowB * 64 + csw * 8]);
            }
#pragma unroll
            for (int m = 0; m < 4; ++m)
#pragma unroll
                for (int n = 0; n < 4; ++n)
                    acc[m][n] = __builtin_amdgcn_mfma_f32_16x16x32_bf16(xh[m], yh[n], acc[m][n], 0, 0, 0);
#pragma unroll
            for (int n = 0; n < 4; ++n) {
                int rowB = wc * 64 + n * 16 + rA;
                t4[n] = *reinterpret_cast<const short8*>(&Bsl[(size_t)rowB * 64 + csw * 8]);
            }
#pragma unroll
            for (int m = 0; m < 4; ++m)
#pragma unroll
                for (int n = 0; n < 4; ++n)
                    acc[m][n] = __builtin_amdgcn_mfma_f32_16x16x32_bf16(xh[m], t4[n], acc[m][n], 0, 0, 0);
#pragma unroll
            for (int m = 0; m < 4; ++m) {
                int rowA = wr * 64 + m * 16 + rA;
                t4[m] = *reinterpret_cast<const short8*>(&Asl[(size_t)rowA * 64 + csw * 8]);
            }
#pragma unroll
            for (int m = 0; m < 4; ++m)
#pragma unroll
                for (int n = 0; n < 4; ++n)
                    acc[m][n] = __builtin_amdgcn_mfma_f32_16x16x32_bf16(t4[m], yh[n], acc[m][n], 0, 0, 0);
        }
        __syncthreads();
    }
#pragma unroll
    for (int n = 0; n < 4; ++n) {
        int gcol = col0 + wc * 64 + n * 16 + rA;
        float bv = bias ? bias[gcol] : 0.f;
#pragma unroll
        for (int m = 0; m < 4; ++m) {
            int grow0 = row0 + wr * 64 + m * 16 + kq * 4;
#pragma unroll
            for (int r = 0; r < 4; ++r) {
                float v = acc[m][n][r] + bv;
                size_t idx = (size_t)(grow0 + r) * ldc + gcol;
                if (C) C[idx] = v;
                if (Chi) {
                    ushort h = f2bf(v);
                    Chi[idx] = h;
                    Clo[idx] = f2bf(v - bf2f(h));
                }
            }
        }
    }
}

// ---------------- FUSED: G = h_in@whhB^T, LSTM pointwise epilogue. Full-size. -------
// M=NPK(20480), N=2048 (B rows = perm_p gate layout), K=512. Flat grid 2560 with
// XCD-aware swizzle. Gate tables UNIT-MAJOR (q=u*4+g): one float4 per table per elem.
// h ping-pong: A (h at t-1) and hbuf (h at t) MUST differ (cross-block race).
__global__ __launch_bounds__(256) void gemm_lstm(
    const ushort* __restrict__ A, const ushort* __restrict__ B,
    const float* __restrict__ relg, const float* __restrict__ entg,
    const int* __restrict__ rel_idx, const int* __restrict__ ent_idx,
    const int* __restrict__ lens_,
    ushort* __restrict__ hbuf, float* __restrict__ cbuf, ushort* __restrict__ pemb,
    int t)
{
    __shared__ ushort As[128 * 64];
    __shared__ ushort Bs[128 * 64];
    const int K = 512;
    int L = blockIdx.x;
    int swz = (L & 7) * 320 + (L >> 3);
    int bx = swz & 15, by = swz >> 4;
    int tid = threadIdx.x;
    int lane = tid & 63;
    int w = tid >> 6;
    int wr = w >> 1, wc = w & 1;
    int col0 = bx * 128, row0 = by * 128;

    f32x4 acc[4][4];
#pragma unroll
    for (int m = 0; m < 4; ++m)
#pragma unroll
        for (int n = 0; n < 4; ++n) acc[m][n] = {0.f, 0.f, 0.f, 0.f};

    int rA = lane & 15;
    int kq = lane >> 4;

    for (int kt = 0; kt < K; kt += 64) {
#pragma unroll
        for (int it = 0; it < 4; ++it) {
            int c = it * 256 + tid;
            int row = c >> 3, ch = c & 7;
            int cs = ch ^ (row & 7);
            uint4 va = *reinterpret_cast<const uint4*>(A + (size_t)(row0 + row) * K + kt + ch * 8);
            *reinterpret_cast<uint4*>(&As[(size_t)row * 64 + cs * 8]) = va;
            uint4 vb = *reinterpret_cast<const uint4*>(B + (size_t)(col0 + row) * K + kt + ch * 8);
            *reinterpret_cast<uint4*>(&Bs[(size_t)row * 64 + cs * 8]) = vb;
        }
        __syncthreads();
#pragma unroll
        for (int s = 0; s < 2; ++s) {
            int csw = (s * 4 + kq) ^ (rA & 7);
            short8 af[4], bfr[4];
#pragma unroll
            for (int m = 0; m < 4; ++m) {
                int rowA = wr * 64 + m * 16 + rA;
                af[m] = *reinterpret_cast<const short8*>(&As[(size_t)rowA * 64 + csw * 8]);
            }
#pragma unroll
            for (int n = 0; n < 4; ++n) {
                int rowB = wc * 64 + n * 16 + rA;
                bfr[n] = *reinterpret_cast<const short8*>(&Bs[(size_t)rowB * 64 + csw * 8]);
            }
#pragma unroll
            for (int m = 0; m < 4; ++m)
#pragma unroll
                for (int n = 0; n < 4; ++n)
                    acc[m][n] = __builtin_amdgcn_mfma_f32_16x16x32_bf16(af[m], bfr[n], acc[m][n], 0, 0, 0);
        }
        __syncthreads();
    }

    // fused LSTM epilogue: lane owns unit u = uh*16+rA; acc[m][0..3] = i,f,g,o gates
    int uh = bx * 2 + wc;
    int u  = uh * 16 + rA;
    const float4* rel4 = reinterpret_cast<const float4*>(relg);
    const float4* ent4 = reinterpret_cast<const float4*>(entg);
#pragma unroll
    for (int m = 0; m < 4; ++m) {
#pragma unroll
        for (int r = 0; r < 4; ++r) {
            int n = row0 + wr * 64 + m * 16 + kq * 4 + r;   // global path row
            int ri = rel_idx[n * 3 + t];
            int ei = ent_idx[n * 3 + t];
            float4 rv = rel4[(size_t)ri * 512 + u];
            float4 ev = ent4[(size_t)ei * 512 + u];
            float gi = acc[m][0][r] + rv.x + ev.x;
            float gf = acc[m][1][r] + rv.y + ev.y;
            float gg = acc[m][2][r] + rv.z + ev.z;
            float go = acc[m][3][r] + rv.w + ev.w;
            float cold = cbuf[(size_t)n * 512 + u];
            float cn = sigf(gf) * cold + sigf(gi) * tanhf_f(gg);
            float hn = sigf(go) * tanhf_f(cn);
            cbuf[(size_t)n * 512 + u] = cn;
            ushort hu = f2bf(hn);
            hbuf[(size_t)n * 512 + u] = hu;
            int len = lens_[n];
            int last = len - 1;
            if (last < 0) last = 0;
            if (last > 2) last = 2;
            if (last == t) pemb[(size_t)n * 512 + u] = (len > 0) ? hu : (ushort)0;
        }
    }
}

// ---------------- LSTM t=0 (no recurrent term), unit-major gate tables --------------
__global__ __launch_bounds__(256) void lstm_t0(
    const float* __restrict__ relg, const float* __restrict__ entg,
    const int* __restrict__ rel_idx, const int* __restrict__ ent_idx,
    const int* __restrict__ lens_,
    ushort* __restrict__ hbuf, float* __restrict__ cbuf, ushort* __restrict__ pemb,
    int nrows)
{
    int gid = blockIdx.x * 256 + threadIdx.x;
    if (gid >= nrows * 128) return;
    int nl = gid >> 7, q = gid & 127;   // units q*4 .. q*4+3
    int ri = rel_idx[nl * 3];
    int ei = ent_idx[nl * 3];
    const float4* rg = reinterpret_cast<const float4*>(relg) + (size_t)ri * 512;
    const float4* eg = reinterpret_cast<const float4*>(entg) + (size_t)ei * 512;
    float4 cn, hn;
#pragma unroll
    for (int j = 0; j < 4; ++j) {
        float4 a = rg[q * 4 + j];
        float4 b = eg[q * 4 + j];
        float gi = a.x + b.x, gg = a.z + b.z, go = a.w + b.w;   // f unused (c0=0)
        float c = sigf(gi) * tanhf_f(gg);
        float h = sigf(go) * tanhf_f(c);
        (&cn.x)[j] = c;
        (&hn.x)[j] = h;
    }
    reinterpret_cast<float4*>(cbuf + (size_t)nl * 512)[q] = cn;
    ushort4 hu = make_ushort4(f2bf(hn.x), f2bf(hn.y), f2bf(hn.z), f2bf(hn.w));
    reinterpret_cast<ushort4*>(hbuf + (size_t)nl * 512)[q] = hu;
    int len = lens_[nl];
    int last = len - 1;
    if (last < 0) last = 0;
    if (last > 2) last = 2;
    if (last == 0) {
        ushort4 pv = (len > 0) ? hu : make_ushort4(0, 0, 0, 0);
        reinterpret_cast<ushort4*>(pemb + (size_t)nl * 512)[q] = pv;
    }
}

// ---------------- per-pair attention -> mean-over-q context (bf16 hi/lo out) --------
__global__ __launch_bounds__(256) void attn_kernel(const float* __restrict__ qkv,
                                                   ushort* __restrict__ mch,
                                                   ushort* __restrict__ mcl, int pair0)
{
    __shared__ float qk[10][1024];
    __shared__ float sc[4][10][10];
    __shared__ float wb[4][10];
    int tid = threadIdx.x;
    const float* base = qkv + (size_t)blockIdx.x * 10 * 1536;
    for (int i = tid; i < 2560; i += 256) {
        int row = i >> 8, c4 = i & 255;
        reinterpret_cast<float4*>(&qk[row][0])[c4] =
            reinterpret_cast<const float4*>(base + (size_t)row * 1536)[c4];
    }
    __syncthreads();
    const float scale = 0.08838834764831845f; // 1/sqrt(128)
    for (int idx = tid; idx < 400; idx += 256) {
        int h = idx / 100, rem = idx % 100, qi = rem / 10, ki = rem % 10;
        const float* qp = &qk[qi][h * 128];
        const float* kp = &qk[ki][512 + h * 128];
        float a = 0.f;
        for (int d = 0; d < 128; ++d) a += qp[d] * kp[d];
        sc[h][qi][ki] = a * scale;
    }
    __syncthreads();
    if (tid < 40) {
        int h = tid / 10, qi = tid % 10;
        float m = -1e30f;
        for (int ki = 0; ki < 10; ++ki) m = fmaxf(m, sc[h][qi][ki]);
        float ex[10]; float s = 0.f;
        for (int ki = 0; ki < 10; ++ki) { ex[ki] = fexp2(LOG2E * (sc[h][qi][ki] - m)); s += ex[ki]; }
        float inv = frcp(s);
        for (int ki = 0; ki < 10; ++ki) sc[h][qi][ki] = ex[ki] * inv;
    }
    __syncthreads();
    if (tid < 40) {
        int h = tid / 10, ki = tid % 10;
        float s = 0.f;
        for (int qi = 0; qi < 10; ++qi) s += sc[h][qi][ki];
        wb[h][ki] = s * 0.1f;
    }
    __syncthreads();
    for (int e = tid; e < 512; e += 256) {
        int h = e >> 7, d = e & 127;
        float a = 0.f;
        for (int ki = 0; ki < 10; ++ki)
            a += wb[h][ki] * base[(size_t)ki * 1536 + 1024 + h * 128 + d];
        size_t idx = (size_t)(pair0 + blockIdx.x) * 512 + e;
        ushort hh = f2bf(a);
        mch[idx] = hh;
        mcl[idx] = f2bf(a - bf2f(hh));
    }
}

extern "C" void kernel_launch(void* const* d_in, const int* in_sizes, int n_in,
                              void* d_out, int out_size, void* d_ws, size_t ws_size,
                              hipStream_t stream)
{
    const int* rel_idx     = (const int*)d_in[0];
    const int* ent_idx     = (const int*)d_in[1];
    const int* path_lens   = (const int*)d_in[2];
    const float* rel_table = (const float*)d_in[3];
    const float* ent_table = (const float*)d_in[4];
    const float* kg_proj_w = (const float*)d_in[5];
    const float* kg_proj_b = (const float*)d_in[6];
    const float* w_ih      = (const float*)d_in[7];
    const float* w_hh      = (const float*)d_in[8];
    const float* b_ih      = (const float*)d_in[9];
    const float* b_hh      = (const float*)d_in[10];
    const float* attn_in_w = (const float*)d_in[11];
    const float* attn_in_b = (const float*)d_in[12];
    const float* attn_out_w = (const float*)d_in[13];
    const float* attn_out_b = (const float*)d_in[14];
    const float* path_proj_w = (const float*)d_in[15];
    const float* path_proj_b = (const float*)d_in[16];
    float* out = (float*)d_out;
    (void)in_sizes; (void)n_in; (void)out_size; (void)ws_size;

    float* ws = (float*)d_ws;
    size_t off = 0;
    auto alloc = [&](size_t n) { float* p = ws + off; off += (n + 63) & ~(size_t)63; return p; };
    // ---- persistent (float units) ----
    int*    perm_p = (int*)alloc(2048);
    int*    perm_q = (int*)alloc(2048);
    float*  bihh   = alloc(2048);
    float*  bcomb  = alloc(512);
    float*  relg   = alloc((size_t)REL_PAD * 2048);       // 2 MB (unit-major cols)
    float*  entg   = alloc((size_t)ENT_PAD * 2048);       // 82.8 MB (unit-major cols)
    ushort* whhB   = (ushort*)alloc((size_t)2048 * 256);  // 2048x512 bf16, perm_p rows
    ushort* aiwB   = (ushort*)alloc((size_t)1536 * 256);
    ushort* pch    = (ushort*)alloc((size_t)NPK * 256);   // pemb bf16, 21 MB
    ushort* Wch    = (ushort*)alloc((size_t)512 * 256);
    ushort* Wcl    = (ushort*)alloc((size_t)512 * 256);
    ushort* mch    = (ushort*)alloc((size_t)PP * 256);    // mctx hi
    ushort* mcl    = (ushort*)alloc((size_t)PP * 256);    // mctx lo
    // ---- phase-shared region (84 MB) ----
    float* R = alloc((size_t)21000000);

    // phase P (prologue temps) — dead before LSTM starts
    size_t ro = 0;
    auto ral = [&](size_t n) { float* p = R + ro; ro += n; return p; };
    ushort* kgWh  = (ushort*)ral(65536);   ushort* kgWl  = (ushort*)ral(65536);
    ushort* relBh = (ushort*)ral(32768);   ushort* relBl = (ushort*)ral(32768);
    ushort* entBh = (ushort*)ral(1294336); ushort* entBl = (ushort*)ral(1294336);
    ushort* wrelh = (ushort*)ral(524288);  ushort* wrell = (ushort*)ral(524288);
    ushort* wenth = (ushort*)ral(524288);  ushort* wentl = (ushort*)ral(524288);
    ushort* rel_ph = (ushort*)ral(65536);   ushort* rel_pl = (ushort*)ral(65536);
    ushort* ent_ph = (ushort*)ral(2588672); ushort* ent_pl = (ushort*)ral(2588672);
    float*  aoT    = ral(262144);
    ushort* pph  = (ushort*)ral(131072); ushort* ppl  = (ushort*)ral(131072);
    ushort* aoTh = (ushort*)ral(131072); ushort* aoTl = (ushort*)ral(131072);
    // phase L (LSTM): fp32 c + h ping-pong — overlays phase P
    float*  cb = R;                               // 20480*512 fp32
    ushort* hA = (ushort*)(R + 10485760);
    ushort* hB = (ushort*)(R + 15728640);
    // phase A (attn): qkv half = 10240*1536 fp32 — overlays phase L
    float*  qkv = R;

    auto split = [&](const float* src, int lda, int col0, ushort* hi, ushort* lo,
                     int nsrc, int ncols, int ndst, const int* pm) {
        int total = ndst * (ncols / 4);
        f2bf_split2d<<<(total + 255) / 256, 256, 0, stream>>>(src, lda, col0, hi, lo, nsrc, ncols, ndst, pm);
    };
    auto gemms = [&](const ushort* Ah, const ushort* Al, const ushort* Bh, const ushort* Bl,
                     float* Cp, ushort* Chi, ushort* Clo,
                     int M, int N, int Kd, int ldc, const float* bias) {
        gemm_bf16s<<<dim3((unsigned)(N / 128), (unsigned)(M / 128)), 256, 0, stream>>>(
            Ah, Al, Bh, Bl, Cp, Chi, Clo, M, N, Kd, ldc, bias);
    };

    // ======== prologue ========
    perm_bias2<<<8, 256, 0, stream>>>(perm_p, perm_q, bihh, b_ih, b_hh);
    transpose_k<<<dim3(16, 16), 256, 0, stream>>>(attn_out_w, aoT, 512, 512);
    split(kg_proj_w, 256, 0, kgWh, kgWl, 512, 256, 512, nullptr);
    split(rel_table, 256, 0, relBh, relBl, 200, 256, REL_PAD, nullptr);
    split(ent_table, 256, 0, entBh, entBl, 10000, 256, ENT_PAD, nullptr);
    split(w_ih, 1024, 0,   wrelh, wrell, 2048, 512, 2048, perm_q);   // table-build B: q layout
    split(w_ih, 1024, 512, wenth, wentl, 2048, 512, 2048, perm_q);
    split(path_proj_w, 512, 0, pph, ppl, 512, 512, 512, nullptr);
    split(aoT, 512, 0, aoTh, aoTl, 512, 512, 512, nullptr);
    f2bf_perm_rows<<<1024, 256, 0, stream>>>(w_hh, whhB, perm_p, 2048, 128); // GEMM B: p layout
    f2bf_k<<<768, 256, 0, stream>>>(attn_in_w, aiwB, 1536 * 128);
    rowdot<<<128, 256, 0, stream>>>(path_proj_w, 512, attn_out_b, 512, path_proj_b, bcomb, 512);

    // projected tables (hi/lo direct): rel_p = relT@kgW^T + b ; ent_p likewise
    gemms(relBh, relBl, kgWh, kgWl, nullptr, rel_ph, rel_pl, REL_PAD, 512, 256, 512, kg_proj_b);
    gemms(entBh, entBl, kgWh, kgWl, nullptr, ent_ph, ent_pl, ENT_PAD, 512, 256, 512, kg_proj_b);
    // gate tables (unit-major cols): relg = rel_p@Wq^T + bihh ; entg = ent_p@Wq^T
    gemms(rel_ph, rel_pl, wrelh, wrell, relg, nullptr, nullptr, REL_PAD, 2048, 512, 2048, bihh);
    gemms(ent_ph, ent_pl, wenth, wentl, entg, nullptr, nullptr, ENT_PAD, 2048, 512, 2048, nullptr);
    // Wcomb = path_proj_w @ attn_out_w (hi/lo direct)
    gemms(pph, ppl, aoTh, aoTl, nullptr, Wch, Wcl, 512, 512, 512, 512, nullptr);

    // ======== LSTM, full-size ========
    lstm_t0<<<(NPK * 128) / 256, 256, 0, stream>>>(
        relg, entg, rel_idx, ent_idx, path_lens, hA, cb, pch, NPK);
    gemm_lstm<<<2560, 256, 0, stream>>>(
        hA, whhB, relg, entg, rel_idx, ent_idx, path_lens, hB, cb, pch, 1);
    gemm_lstm<<<2560, 256, 0, stream>>>(
        hB, whhB, relg, entg, rel_idx, ent_idx, path_lens, hA, cb, pch, 2);

    // ======== qkv + attention, 2 halves ========
    for (int h = 0; h < 2; ++h) {
        gemm_bf16<<<dim3(12, 80), 256, 0, stream>>>(
            pch + (size_t)h * HALF_ROWS * 512, aiwB, qkv, HALF_ROWS, 1536, 512, 1536, attn_in_b);
        attn_kernel<<<HALF_PAIRS, 256, 0, stream>>>(qkv, mch, mcl, h * HALF_PAIRS);
    }

    // ======== out = mctx @ Wcomb^T + bcomb (split-bf16) ========
    gemms(mch, mcl, Wch, Wcl, out, nullptr, nullptr, 2048, 512, 512, 512, bcomb);
}